// Round 6
// baseline (104.068 us; speedup 1.0000x reference)
//
#include <hip/hip_runtime.h>
#include <math.h>

// Canny front-end, LDS-free register streaming, R=4 strips.
// R5 post-mortem: 1024 blocks = 16 waves/CU = 50% occupancy cap, each wave a
// 14-row serial chain -> latency-limited at ~2.3 TB/s effective. Halving the
// strip doubles block count (2048 = 32 waves/CU demand) and shortens the
// chain to 10 rows. Halo over-read rises to 2.5x raw (80 MB) but the
// contiguous-strips-per-XCD swizzle keeps adjacent strips co-resident on one
// XCD so shared rows (6 of 10) can hit L2.
// NO min-waves __launch_bounds__ (R4: forcing 64 VGPR spilled ~64 MB scratch).

#define H_IMG 1024
#define W_IMG 1024
#define W4 (W_IMG / 4)   // 256 float4 columns = one block spans full width
#define R 4              // output rows per strip; window = R+6 = 10 rows
#define NSTRIP (H_IMG / R)   // 256 strips per image

__global__ __launch_bounds__(256) void canny_stream(
    const float* __restrict__ img,
    const float* __restrict__ gauss,   // 5 taps [g0,g1,g2,g1,g0]
    float* __restrict__ out)
{
    const int j = threadIdx.x;             // float4 column index 0..255

    // ---- XCD-aware strip assignment: 32 contiguous strips per XCD per image.
    // Assumes round-robin blockIdx->XCD; perf heuristic only, never correctness.
    const int bid   = blockIdx.x;          // 0..2047
    const int xcd   = bid & 7;
    const int slot  = bid >> 3;            // 0..255
    const int b     = slot >> 5;           // image 0..7
    const int strip = xcd * 32 + (slot & 31);   // 0..255, contiguous per XCD
    const int y0    = strip * R;

    const float g0 = gauss[0], g1 = gauss[1], g2 = gauss[2];
    const float* __restrict__ imgb = img + (size_t)b * (H_IMG * W_IMG);
    float* __restrict__ outb       = out + (size_t)b * (H_IMG * W_IMG);
    const int xc = 4 * j;

    float hb[5][6];   // h-blurred rows, cols xc-1..xc+4 ; row (y0-3+it) at slot it%5
    float bl[3][6];   // blurred rows                    ; row (y0-5+it) at slot (it-4)%3

    #pragma unroll
    for (int it = 0; it < R + 6; ++it) {
        // ---- ingest raw row ry, h-blur into window ----
        const int ry = y0 - 3 + it;
        float* h = hb[it % 5];
        if (ry >= 0 && ry < H_IMG) {
            const float* p = imgb + ry * W_IMG + xc;
            float4 A = make_float4(0.f, 0.f, 0.f, 0.f);
            float4 C = make_float4(0.f, 0.f, 0.f, 0.f);
            if (j > 0)      A = *(const float4*)(p - 4);   // cols xc-4..xc-1
            float4 B = *(const float4*)(p);                // cols xc  ..xc+3
            if (j < W4 - 1) C = *(const float4*)(p + 4);   // cols xc+4..xc+7
            h[0] = g0 * (A.y + B.y) + g1 * (A.z + B.x) + g2 * A.w;  // col xc-1
            h[1] = g0 * (A.z + B.z) + g1 * (A.w + B.y) + g2 * B.x;  // col xc
            h[2] = g0 * (A.w + B.w) + g1 * (B.x + B.z) + g2 * B.y;  // col xc+1
            h[3] = g0 * (B.x + C.x) + g1 * (B.y + B.w) + g2 * B.z;  // col xc+2
            h[4] = g0 * (B.y + C.y) + g1 * (B.z + C.x) + g2 * B.w;  // col xc+3
            h[5] = g0 * (B.z + C.z) + g1 * (B.w + C.y) + g2 * C.x;  // col xc+4
        } else {
            #pragma unroll
            for (int k = 0; k < 6; ++k) h[k] = 0.0f;   // v-conv zero-pad of t rows
        }

        // ---- v-blur: once 5 hb rows live, produce blurred row by = ry-2 ----
        if (it >= 4) {
            const int by = ry - 2;
            float* o = bl[(it - 4) % 3];
            if (by >= 0 && by < H_IMG) {
                const float* h0 = hb[(it - 4) % 5];   // t(by-2)
                const float* h1 = hb[(it - 3) % 5];   // t(by-1)
                const float* h2 = hb[(it - 2) % 5];   // t(by)
                const float* h3 = hb[(it - 1) % 5];   // t(by+1)
                const float* h4 = hb[(it    ) % 5];   // t(by+2)
                #pragma unroll
                for (int k = 0; k < 6; ++k)
                    o[k] = g0 * (h0[k] + h4[k]) + g1 * (h1[k] + h3[k]) + g2 * h2[k];
                // sobel's zero-pad of blurred COLUMNS:
                if (j == 0)      o[0] = 0.0f;   // blurred col -1
                if (j == W4 - 1) o[5] = 0.0f;   // blurred col 1024
            } else {
                #pragma unroll
                for (int k = 0; k < 6; ++k) o[k] = 0.0f;  // sobel zero-pad of rows
            }
        }

        // ---- sobel + mag + threshold on output row oy = ry-3 ----
        if (it >= 6) {
            const int oy = ry - 3;                       // in [y0, y0+R-1]
            const float* T  = bl[(it - 6) % 3];          // blurred(oy-1)
            const float* M  = bl[(it - 5) % 3];          // blurred(oy)
            const float* Bo = bl[(it - 4) % 3];          // blurred(oy+1)
            float4 o4;
            float* po = (float*)&o4;
            #pragma unroll
            for (int k = 0; k < 4; ++k) {                // out col xc+k -> idx k..k+2
                float gx = (T[k] - T[k + 2]) + 2.0f * (M[k] - M[k + 2]) + (Bo[k] - Bo[k + 2]);
                float gy = (T[k] + 2.0f * T[k + 1] + T[k + 2])
                         - (Bo[k] + 2.0f * Bo[k + 1] + Bo[k + 2]);
                float mag = sqrtf(gx * gx + gy * gy);
                po[k] = (mag < 2.0f) ? 0.0f : mag;
            }
            *(float4*)(outb + oy * W_IMG + xc) = o4;
        }
    }
}

extern "C" void kernel_launch(void* const* d_in, const int* in_sizes, int n_in,
                              void* d_out, int out_size, void* d_ws, size_t ws_size,
                              hipStream_t stream) {
    const float* img   = (const float*)d_in[0];
    const float* gauss = (const float*)d_in[1];
    float* out = (float*)d_out;
    const int N = in_sizes[0] / (H_IMG * W_IMG);   // = 8

    dim3 grid(NSTRIP * N);                         // 2048 blocks, swizzled in-kernel
    canny_stream<<<grid, 256, 0, stream>>>(img, gauss, out);
}

// Round 7
// 102.483 us; speedup vs baseline: 1.0155x; 1.0155x over previous
//
#include <hip/hip_runtime.h>
#include <math.h>

// Canny front-end, register-streaming, macro-unrolled, branch-free interior.
// R4 retry WITHOUT the min-waves launch bound: __launch_bounds__(256,4) had
// forced 64 VGPR and spilled the rolling windows to scratch (WRITE_SIZE
// 96 MB = 3x output). Natural allocation keeps hb/bl in registers while the
// straight-line fast path lets the scheduler hoist/pipeline all 42 row loads
// across rows (the R3/R5/R6 per-row bounds branches blocked that, leaving
// each wave load->wait->compute serialized at ~2.6 TB/s effective).
//
// Semantics per reference: h-conv zero-pads img columns; v-conv zero-pads
// t rows; sobel zero-pads blurred rows AND columns.

#define H_IMG 1024
#define W_IMG 1024
#define W4 (W_IMG / 4)
#define R 8

// ---- h-blur one raw row into H[6] = h-blurred cols xc-1 .. xc+4 ----
#define HROW_F(H, RY)                                                       \
    {                                                                       \
        const float* p_  = imgb + (RY) * W_IMG + xc;                        \
        const float* pa_ = (j > 0)      ? p_ - 4 : p_;                      \
        const float* pc_ = (j < W4 - 1) ? p_ + 4 : p_;                      \
        float4 A = *(const float4*)pa_;                                     \
        float4 B = *(const float4*)p_;                                      \
        float4 C = *(const float4*)pc_;                                     \
        if (j == 0)      A = zero4;                                         \
        if (j == W4 - 1) C = zero4;                                         \
        H[0] = g0 * (A.y + B.y) + g1 * (A.z + B.x) + g2 * A.w;              \
        H[1] = g0 * (A.z + B.z) + g1 * (A.w + B.y) + g2 * B.x;              \
        H[2] = g0 * (A.w + B.w) + g1 * (B.x + B.z) + g2 * B.y;              \
        H[3] = g0 * (B.x + C.x) + g1 * (B.y + B.w) + g2 * B.z;              \
        H[4] = g0 * (B.y + C.y) + g1 * (B.z + C.x) + g2 * B.w;              \
        H[5] = g0 * (B.z + C.z) + g1 * (B.w + C.y) + g2 * C.x;              \
    }

#define HROW_C(H, RY)                                                       \
    {                                                                       \
        if ((RY) >= 0 && (RY) < H_IMG) {                                    \
            HROW_F(H, RY)                                                   \
        } else {                                                            \
            H[0] = H[1] = H[2] = H[3] = H[4] = H[5] = 0.0f;                 \
        }                                                                   \
    }

// ---- v-blur 5 t-rows into O[6]; zero blurred edge columns (sobel pad) ----
#define VBLUR_F(O, Ha, Hb, Hc, Hd, He)                                      \
    {                                                                       \
        O[0] = g0 * (Ha[0] + He[0]) + g1 * (Hb[0] + Hd[0]) + g2 * Hc[0];    \
        O[1] = g0 * (Ha[1] + He[1]) + g1 * (Hb[1] + Hd[1]) + g2 * Hc[1];    \
        O[2] = g0 * (Ha[2] + He[2]) + g1 * (Hb[2] + Hd[2]) + g2 * Hc[2];    \
        O[3] = g0 * (Ha[3] + He[3]) + g1 * (Hb[3] + Hd[3]) + g2 * Hc[3];    \
        O[4] = g0 * (Ha[4] + He[4]) + g1 * (Hb[4] + Hd[4]) + g2 * Hc[4];    \
        O[5] = g0 * (Ha[5] + He[5]) + g1 * (Hb[5] + Hd[5]) + g2 * Hc[5];    \
        if (j == 0)      O[0] = 0.0f;                                       \
        if (j == W4 - 1) O[5] = 0.0f;                                       \
    }

#define VBLUR_C(O, BY, Ha, Hb, Hc, Hd, He)                                  \
    {                                                                       \
        if ((BY) >= 0 && (BY) < H_IMG) {                                    \
            VBLUR_F(O, Ha, Hb, Hc, Hd, He)                                  \
        } else {                                                            \
            O[0] = O[1] = O[2] = O[3] = O[4] = O[5] = 0.0f;                 \
        }                                                                   \
    }

// ---- sobel + magnitude + threshold for one output element ----
#define SOB1(T, M, Bo, K, DST)                                              \
    {                                                                       \
        float gx_ = (T[K] - T[K + 2]) + 2.0f * (M[K] - M[K + 2])            \
                  + (Bo[K] - Bo[K + 2]);                                    \
        float gy_ = (T[K] + 2.0f * T[K + 1] + T[K + 2])                     \
                  - (Bo[K] + 2.0f * Bo[K + 1] + Bo[K + 2]);                 \
        float mg_ = sqrtf(gx_ * gx_ + gy_ * gy_);                           \
        DST = (mg_ < 2.0f) ? 0.0f : mg_;                                    \
    }

#define SOBEL(OY, T, M, Bo)                                                 \
    {                                                                       \
        float4 o4_;                                                         \
        SOB1(T, M, Bo, 0, o4_.x)                                            \
        SOB1(T, M, Bo, 1, o4_.y)                                            \
        SOB1(T, M, Bo, 2, o4_.z)                                            \
        SOB1(T, M, Bo, 3, o4_.w)                                            \
        *(float4*)(outb + (OY) * W_IMG + xc) = o4_;                         \
    }

__global__ __launch_bounds__(256) void canny_stream3(
    const float* __restrict__ img,
    const float* __restrict__ gauss,   // 5 taps [g0,g1,g2,g1,g0]
    float* __restrict__ out)
{
    const int j  = threadIdx.x;          // float4 column 0..255
    const int y0 = blockIdx.x * R;       // first output row of this strip
    const int b  = blockIdx.y;

    const float g0 = gauss[0], g1 = gauss[1], g2 = gauss[2];
    const float* __restrict__ imgb = img + (size_t)b * (H_IMG * W_IMG);
    float* __restrict__ outb       = out + (size_t)b * (H_IMG * W_IMG);
    const int xc = 4 * j;
    const float4 zero4 = make_float4(0.0f, 0.0f, 0.0f, 0.0f);

    float hb0[6], hb1[6], hb2[6], hb3[6], hb4[6];
    float bl0[6], bl1[6], bl2[6];

    if (y0 >= 3 && y0 + 10 < H_IMG) {
        // ---------- fast path: all 14 raw rows in-bounds, zero branches ----
        HROW_F(hb0, y0 - 3)
        HROW_F(hb1, y0 - 2)
        HROW_F(hb2, y0 - 1)
        HROW_F(hb3, y0    )
        HROW_F(hb4, y0 + 1)  VBLUR_F(bl0, hb0, hb1, hb2, hb3, hb4)
        HROW_F(hb0, y0 + 2)  VBLUR_F(bl1, hb1, hb2, hb3, hb4, hb0)
        HROW_F(hb1, y0 + 3)  VBLUR_F(bl2, hb2, hb3, hb4, hb0, hb1)
        SOBEL(y0,     bl0, bl1, bl2)
        HROW_F(hb2, y0 + 4)  VBLUR_F(bl0, hb3, hb4, hb0, hb1, hb2)
        SOBEL(y0 + 1, bl1, bl2, bl0)
        HROW_F(hb3, y0 + 5)  VBLUR_F(bl1, hb4, hb0, hb1, hb2, hb3)
        SOBEL(y0 + 2, bl2, bl0, bl1)
        HROW_F(hb4, y0 + 6)  VBLUR_F(bl2, hb0, hb1, hb2, hb3, hb4)
        SOBEL(y0 + 3, bl0, bl1, bl2)
        HROW_F(hb0, y0 + 7)  VBLUR_F(bl0, hb1, hb2, hb3, hb4, hb0)
        SOBEL(y0 + 4, bl1, bl2, bl0)
        HROW_F(hb1, y0 + 8)  VBLUR_F(bl1, hb2, hb3, hb4, hb0, hb1)
        SOBEL(y0 + 5, bl2, bl0, bl1)
        HROW_F(hb2, y0 + 9)  VBLUR_F(bl2, hb3, hb4, hb0, hb1, hb2)
        SOBEL(y0 + 6, bl0, bl1, bl2)
        HROW_F(hb3, y0 + 10) VBLUR_F(bl0, hb4, hb0, hb1, hb2, hb3)
        SOBEL(y0 + 7, bl1, bl2, bl0)
    } else {
        // ---------- edge strips (2 of 128): per-row bounds ----------
        HROW_C(hb0, y0 - 3)
        HROW_C(hb1, y0 - 2)
        HROW_C(hb2, y0 - 1)
        HROW_C(hb3, y0    )
        HROW_C(hb4, y0 + 1)  VBLUR_C(bl0, y0 - 1, hb0, hb1, hb2, hb3, hb4)
        HROW_C(hb0, y0 + 2)  VBLUR_C(bl1, y0,     hb1, hb2, hb3, hb4, hb0)
        HROW_C(hb1, y0 + 3)  VBLUR_C(bl2, y0 + 1, hb2, hb3, hb4, hb0, hb1)
        SOBEL(y0,     bl0, bl1, bl2)
        HROW_C(hb2, y0 + 4)  VBLUR_C(bl0, y0 + 2, hb3, hb4, hb0, hb1, hb2)
        SOBEL(y0 + 1, bl1, bl2, bl0)
        HROW_C(hb3, y0 + 5)  VBLUR_C(bl1, y0 + 3, hb4, hb0, hb1, hb2, hb3)
        SOBEL(y0 + 2, bl2, bl0, bl1)
        HROW_C(hb4, y0 + 6)  VBLUR_C(bl2, y0 + 4, hb0, hb1, hb2, hb3, hb4)
        SOBEL(y0 + 3, bl0, bl1, bl2)
        HROW_C(hb0, y0 + 7)  VBLUR_C(bl0, y0 + 5, hb1, hb2, hb3, hb4, hb0)
        SOBEL(y0 + 4, bl1, bl2, bl0)
        HROW_C(hb1, y0 + 8)  VBLUR_C(bl1, y0 + 6, hb2, hb3, hb4, hb0, hb1)
        SOBEL(y0 + 5, bl2, bl0, bl1)
        HROW_C(hb2, y0 + 9)  VBLUR_C(bl2, y0 + 7, hb3, hb4, hb0, hb1, hb2)
        SOBEL(y0 + 6, bl0, bl1, bl2)
        HROW_C(hb3, y0 + 10) VBLUR_C(bl0, y0 + 8, hb4, hb0, hb1, hb2, hb3)
        SOBEL(y0 + 7, bl1, bl2, bl0)
    }
}

extern "C" void kernel_launch(void* const* d_in, const int* in_sizes, int n_in,
                              void* d_out, int out_size, void* d_ws, size_t ws_size,
                              hipStream_t stream) {
    const float* img   = (const float*)d_in[0];
    const float* gauss = (const float*)d_in[1];
    float* out = (float*)d_out;
    const int N = in_sizes[0] / (H_IMG * W_IMG);   // = 8

    dim3 grid(H_IMG / R, N);                       // (128, 8) = 1024 blocks
    canny_stream3<<<grid, 256, 0, stream>>>(img, gauss, out);
}